// Round 6
// baseline (120.038 us; speedup 1.0000x reference)
//
#include <hip/hip_runtime.h>
#include <float.h>
#include <math.h>

#define F_MAX 512
#define RED_BLOCKS 32
#define COPY_GRID 2048

typedef float f4 __attribute__((ext_vector_type(4)));

// ---------------------------------------------------------------------------
// K1: block 0 = frame math only (quaternion normalize, qmult, t_all, gather
// by opt_frames, tdiff/qdiff). Blocks 1..RED_BLOCKS = per-component min/max
// partials over (iv+vp), f4-vectorized. Critical path = max, not sum.
// ---------------------------------------------------------------------------
__global__ __launch_bounds__(256) void minmax_frames_kernel(
    const f4* __restrict__ iv4, const f4* __restrict__ vp4, int nv4,
    float* __restrict__ partial,
    const float* __restrict__ tr,   // (1,1,F,3)
    const float* __restrict__ q,    // (1,F,4)
    const float* __restrict__ off,  // (1,1,F,7)
    const int*   __restrict__ of,   // (F,)
    float* __restrict__ out_t,      // (F,3)
    float* __restrict__ out_q,      // (F,4)
    float* __restrict__ out_td,     // (F,)
    float* __restrict__ out_qd,     // (F,)
    int F)
{
    const int t = threadIdx.x;

    if (blockIdx.x != 0) {
        // ---- min/max partial reduction, f4-vectorized ----
        // element 4*i+j has component (i+j)%3
        float mx0=-FLT_MAX, mx1=-FLT_MAX, mx2=-FLT_MAX;
        float mn0= FLT_MAX, mn1= FLT_MAX, mn2= FLT_MAX;
        const int gstride = (gridDim.x - 1) * blockDim.x;
        for (int i = (blockIdx.x - 1) * blockDim.x + t; i < nv4; i += gstride) {
            f4 a = iv4[i] + vp4[i];
            switch (i % 3) {
            case 0:
                mx0=fmaxf(mx0,a[0]); mn0=fminf(mn0,a[0]);
                mx1=fmaxf(mx1,a[1]); mn1=fminf(mn1,a[1]);
                mx2=fmaxf(mx2,a[2]); mn2=fminf(mn2,a[2]);
                mx0=fmaxf(mx0,a[3]); mn0=fminf(mn0,a[3]);
                break;
            case 1:
                mx1=fmaxf(mx1,a[0]); mn1=fminf(mn1,a[0]);
                mx2=fmaxf(mx2,a[1]); mn2=fminf(mn2,a[1]);
                mx0=fmaxf(mx0,a[2]); mn0=fminf(mn0,a[2]);
                mx1=fmaxf(mx1,a[3]); mn1=fminf(mn1,a[3]);
                break;
            default:
                mx2=fmaxf(mx2,a[0]); mn2=fminf(mn2,a[0]);
                mx0=fmaxf(mx0,a[1]); mn0=fminf(mn0,a[1]);
                mx1=fmaxf(mx1,a[2]); mn1=fminf(mn1,a[2]);
                mx2=fmaxf(mx2,a[3]); mn2=fminf(mn2,a[3]);
                break;
            }
        }
        __shared__ float s[256][6];
        s[t][0]=mx0; s[t][1]=mx1; s[t][2]=mx2; s[t][3]=mn0; s[t][4]=mn1; s[t][5]=mn2;
        __syncthreads();
        for (int w = 128; w >= 1; w >>= 1) {
            if (t < w) {
                s[t][0] = fmaxf(s[t][0], s[t+w][0]);
                s[t][1] = fmaxf(s[t][1], s[t+w][1]);
                s[t][2] = fmaxf(s[t][2], s[t+w][2]);
                s[t][3] = fminf(s[t][3], s[t+w][3]);
                s[t][4] = fminf(s[t][4], s[t+w][4]);
                s[t][5] = fminf(s[t][5], s[t+w][5]);
            }
            __syncthreads();
        }
        if (t == 0) {
            #pragma unroll
            for (int k = 0; k < 6; ++k)
                partial[(blockIdx.x - 1)*6 + k] = s[0][k];
        }
        return;
    }

    // ---- frame math (block 0 only) ----
    __shared__ float qall[F_MAX][4];
    __shared__ float tall[F_MAX][3];

    for (int f = t; f < F; f += blockDim.x) {
        float w1 = q[4*f+0], x1 = q[4*f+1], y1 = q[4*f+2], z1 = q[4*f+3];
        float n1 = sqrtf(w1*w1 + x1*x1 + y1*y1 + z1*z1);
        w1 /= n1; x1 /= n1; y1 /= n1; z1 /= n1;
        float w0 = off[7*f+3], x0 = off[7*f+4], y0 = off[7*f+5], z0 = off[7*f+6];
        float n0 = sqrtf(w0*w0 + x0*x0 + y0*y0 + z0*z0);
        w0 /= n0; x0 /= n0; y0 /= n0; z0 /= n0;
        float pw = -x1*x0 - y1*y0 - z1*z0 + w1*w0;
        float px =  x1*w0 + y1*z0 - z1*y0 + w1*x0;
        float py = -x1*z0 + y1*w0 + z1*x0 + w1*y0;
        float pz =  x1*y0 - y1*x0 + z1*w0 + w1*z0;
        if (f == 0) { pw = w1; px = x1; py = y1; pz = z1; }  // q_all[0] = qn[0]
        qall[f][0] = pw; qall[f][1] = px; qall[f][2] = py; qall[f][3] = pz;
        float o0 = 0.f, o1 = 0.f, o2 = 0.f;
        if (f >= 1) { o0 = off[7*f+0]; o1 = off[7*f+1]; o2 = off[7*f+2]; }
        tall[f][0] = tr[3*f+0] + o0;
        tall[f][1] = tr[3*f+1] + o1;
        tall[f][2] = tr[3*f+2] + o2;
    }
    __syncthreads();

    for (int j = t; j < F; j += blockDim.x) {
        const int fj = of[j];
        out_t[3*j+0] = tall[fj][0];
        out_t[3*j+1] = tall[fj][1];
        out_t[3*j+2] = tall[fj][2];
        out_q[4*j+0] = qall[fj][0];
        out_q[4*j+1] = qall[fj][1];
        out_q[4*j+2] = qall[fj][2];
        out_q[4*j+3] = qall[fj][3];

        float wj = (j == 0) ? 0.0f : (float)(of[j] - of[j-1]);

        float td = 0.0f;
        if (j >= 1) {
            const int fp = of[j-1];
            float ssum = 0.0f;
            #pragma unroll
            for (int c = 0; c < 3; ++c) {
                float d = fabsf(tall[fj][c] - tall[fp][c]);
                if (d < 0.2f) d = 0.0f;
                ssum += d * d;
            }
            td = wj * sqrtf(ssum);
        }
        out_td[j] = td;

        float qd;
        if (j == 0) {
            float sm = qall[F-1][0]*qall[F-1][0] + qall[F-1][1]*qall[F-1][1]
                     + qall[F-1][2]*qall[F-1][2] + qall[F-1][3]*qall[F-1][3];
            qd = wj * (1.0f - sm*sm);   // wj == 0
        } else {
            int ia = fj - 1;
            if (ia < 0) ia += F;        // JAX negative-index wrap
            float sm = qall[ia][0]*qall[fj][0] + qall[ia][1]*qall[fj][1]
                     + qall[ia][2]*qall[fj][2] + qall[ia][3]*qall[fj][3];
            qd = wj * (1.0f - sm*sm);
        }
        out_qd[j] = qd;
    }
}

// ---------------------------------------------------------------------------
// K2: texture copy — simple grid-stride, PLAIN load + PLAIN store (this
// round's single A/B change vs R5: NT load -> plain load; m13's 6.29 TB/s
// reference copy is plain+plain grid-stride). L2 write-allocate acts as the
// write-combining buffer (fill kernels sustain 6.9 TB/s with plain stores);
// streaming read lines die in L2 without cost. Vertex normalize runs AFTER
// the copy in the first blocks; finalize recomputed per-thread from the 32
// partials (previous dispatch = coherence point, no grid sync).
// big = max over flattened centered array == max_c fl(mmax_c - center_c)
// (fl(x-c) is monotone in x, so the component max survives centering).
// ---------------------------------------------------------------------------
__global__ __launch_bounds__(256) void copy_finalize_norm_kernel(
    const f4* __restrict__ tex, f4* __restrict__ out_tex, long n_tex4,
    const float* __restrict__ partial,
    const f4* __restrict__ iv4, const f4* __restrict__ vp4,
    f4* __restrict__ out_v, int nv4)
{
    const int t = threadIdx.x;
    const long nthreads = (long)gridDim.x * blockDim.x;

    // ---- texture copy ----
    for (long i = (long)blockIdx.x * blockDim.x + t; i < n_tex4; i += nthreads) {
        out_tex[i] = tex[i];
    }

    // ---- vertex normalize (first ceil(nv4/256) blocks, one f4/thread) ----
    const int gvid = blockIdx.x * blockDim.x + t;
    if (gvid < nv4) {
        float mx0=-FLT_MAX, mx1=-FLT_MAX, mx2=-FLT_MAX;
        float mn0= FLT_MAX, mn1= FLT_MAX, mn2= FLT_MAX;
        #pragma unroll
        for (int b = 0; b < RED_BLOCKS; ++b) {
            mx0 = fmaxf(mx0, partial[6*b+0]);
            mx1 = fmaxf(mx1, partial[6*b+1]);
            mx2 = fmaxf(mx2, partial[6*b+2]);
            mn0 = fminf(mn0, partial[6*b+3]);
            mn1 = fminf(mn1, partial[6*b+4]);
            mn2 = fminf(mn2, partial[6*b+5]);
        }
        const float c0 = (mx0 + mn0) * 0.5f;
        const float c1 = (mx1 + mn1) * 0.5f;
        const float c2 = (mx2 + mn2) * 0.5f;
        const float big = fmaxf(fmaxf(mx0 - c0, mx1 - c1), mx2 - c2);

        f4 a = iv4[gvid] + vp4[gvid];
        f4 r;
        // element 4*gvid+j has component (gvid+j)%3
        switch (gvid % 3) {
        case 0:
            r[0]=(a[0]-c0)/big; r[1]=(a[1]-c1)/big;
            r[2]=(a[2]-c2)/big; r[3]=(a[3]-c0)/big; break;
        case 1:
            r[0]=(a[0]-c1)/big; r[1]=(a[1]-c2)/big;
            r[2]=(a[2]-c0)/big; r[3]=(a[3]-c1)/big; break;
        default:
            r[0]=(a[0]-c2)/big; r[1]=(a[1]-c0)/big;
            r[2]=(a[2]-c1)/big; r[3]=(a[3]-c2)/big; break;
        }
        out_v[gvid] = r;
    }
}

// ---------------------------------------------------------------------------
extern "C" void kernel_launch(void* const* d_in, const int* in_sizes, int n_in,
                              void* d_out, int out_size, void* d_ws, size_t ws_size,
                              hipStream_t stream) {
    const float* tr  = (const float*)d_in[0];   // translation_p (1,1,F,3)
    const float* q   = (const float*)d_in[1];   // quaternion_p  (1,F,4)
    const float* vp  = (const float*)d_in[2];   // vertices_p    (1,V,3)
    const float* tex = (const float*)d_in[3];   // texture_map   (1,NF,T,T)
    const float* iv  = (const float*)d_in[4];   // ivertices     (1,V,3)
    const float* off = (const float*)d_in[5];   // offsets       (1,1,F,7)
    const int*   of  = (const int*)d_in[6];     // opt_frames    (F,)

    const int F    = in_sizes[6];
    const int nt   = in_sizes[0];   // F*3  = 720
    const int nq   = in_sizes[1];   // F*4  = 960
    const int nv   = in_sizes[2];   // V*3  = 300000 (div by 4)
    const int ntex = in_sizes[3];   // 67108864

    float* out     = (float*)d_out;
    float* out_t   = out;
    float* out_q   = out + nt;
    float* out_v   = out + nt + nq;              // float offset 1680   (%4==0)
    float* out_tex = out + nt + nq + nv;         // float offset 301680 (%4==0)
    float* out_td  = out + (size_t)nt + nq + nv + ntex;
    float* out_qd  = out_td + F;

    float* partial = (float*)d_ws;               // RED_BLOCKS*6 floats

    const int nv4 = nv / 4;

    minmax_frames_kernel<<<RED_BLOCKS + 1, 256, 0, stream>>>(
        (const f4*)iv, (const f4*)vp, nv4, partial,
        tr, q, off, of, out_t, out_q, out_td, out_qd, F);

    const long n_tex4 = (long)ntex / 4;
    copy_finalize_norm_kernel<<<COPY_GRID, 256, 0, stream>>>(
        (const f4*)tex, (f4*)out_tex, n_tex4,
        partial, (const f4*)iv, (const f4*)vp, (f4*)out_v, nv4);
}

// Round 7
// 107.606 us; speedup vs baseline: 1.1155x; 1.1155x over previous
//
#include <hip/hip_runtime.h>
#include <float.h>
#include <math.h>

#define F_MAX 512
#define RED_BLOCKS 32
#define COPY_GRID 2048

typedef float f4 __attribute__((ext_vector_type(4)));

// ---------------------------------------------------------------------------
// K1: block 0 = frame math only (quaternion normalize, qmult, t_all, gather
// by opt_frames, tdiff/qdiff). Blocks 1..RED_BLOCKS = per-component min/max
// partials over (iv+vp), f4-vectorized. Critical path = max, not sum.
// ---------------------------------------------------------------------------
__global__ __launch_bounds__(256) void minmax_frames_kernel(
    const f4* __restrict__ iv4, const f4* __restrict__ vp4, int nv4,
    float* __restrict__ partial,
    const float* __restrict__ tr,   // (1,1,F,3)
    const float* __restrict__ q,    // (1,F,4)
    const float* __restrict__ off,  // (1,1,F,7)
    const int*   __restrict__ of,   // (F,)
    float* __restrict__ out_t,      // (F,3)
    float* __restrict__ out_q,      // (F,4)
    float* __restrict__ out_td,     // (F,)
    float* __restrict__ out_qd,     // (F,)
    int F)
{
    const int t = threadIdx.x;

    if (blockIdx.x != 0) {
        // ---- min/max partial reduction, f4-vectorized ----
        // element 4*i+j has component (i+j)%3
        float mx0=-FLT_MAX, mx1=-FLT_MAX, mx2=-FLT_MAX;
        float mn0= FLT_MAX, mn1= FLT_MAX, mn2= FLT_MAX;
        const int gstride = (gridDim.x - 1) * blockDim.x;
        for (int i = (blockIdx.x - 1) * blockDim.x + t; i < nv4; i += gstride) {
            f4 a = iv4[i] + vp4[i];
            switch (i % 3) {
            case 0:
                mx0=fmaxf(mx0,a[0]); mn0=fminf(mn0,a[0]);
                mx1=fmaxf(mx1,a[1]); mn1=fminf(mn1,a[1]);
                mx2=fmaxf(mx2,a[2]); mn2=fminf(mn2,a[2]);
                mx0=fmaxf(mx0,a[3]); mn0=fminf(mn0,a[3]);
                break;
            case 1:
                mx1=fmaxf(mx1,a[0]); mn1=fminf(mn1,a[0]);
                mx2=fmaxf(mx2,a[1]); mn2=fminf(mn2,a[1]);
                mx0=fmaxf(mx0,a[2]); mn0=fminf(mn0,a[2]);
                mx1=fmaxf(mx1,a[3]); mn1=fminf(mn1,a[3]);
                break;
            default:
                mx2=fmaxf(mx2,a[0]); mn2=fminf(mn2,a[0]);
                mx0=fmaxf(mx0,a[1]); mn0=fminf(mn0,a[1]);
                mx1=fmaxf(mx1,a[2]); mn1=fminf(mn1,a[2]);
                mx2=fmaxf(mx2,a[3]); mn2=fminf(mn2,a[3]);
                break;
            }
        }
        __shared__ float s[256][6];
        s[t][0]=mx0; s[t][1]=mx1; s[t][2]=mx2; s[t][3]=mn0; s[t][4]=mn1; s[t][5]=mn2;
        __syncthreads();
        for (int w = 128; w >= 1; w >>= 1) {
            if (t < w) {
                s[t][0] = fmaxf(s[t][0], s[t+w][0]);
                s[t][1] = fmaxf(s[t][1], s[t+w][1]);
                s[t][2] = fmaxf(s[t][2], s[t+w][2]);
                s[t][3] = fminf(s[t][3], s[t+w][3]);
                s[t][4] = fminf(s[t][4], s[t+w][4]);
                s[t][5] = fminf(s[t][5], s[t+w][5]);
            }
            __syncthreads();
        }
        if (t == 0) {
            #pragma unroll
            for (int k = 0; k < 6; ++k)
                partial[(blockIdx.x - 1)*6 + k] = s[0][k];
        }
        return;
    }

    // ---- frame math (block 0 only) ----
    __shared__ float qall[F_MAX][4];
    __shared__ float tall[F_MAX][3];

    for (int f = t; f < F; f += blockDim.x) {
        float w1 = q[4*f+0], x1 = q[4*f+1], y1 = q[4*f+2], z1 = q[4*f+3];
        float n1 = sqrtf(w1*w1 + x1*x1 + y1*y1 + z1*z1);
        w1 /= n1; x1 /= n1; y1 /= n1; z1 /= n1;
        float w0 = off[7*f+3], x0 = off[7*f+4], y0 = off[7*f+5], z0 = off[7*f+6];
        float n0 = sqrtf(w0*w0 + x0*x0 + y0*y0 + z0*z0);
        w0 /= n0; x0 /= n0; y0 /= n0; z0 /= n0;
        float pw = -x1*x0 - y1*y0 - z1*z0 + w1*w0;
        float px =  x1*w0 + y1*z0 - z1*y0 + w1*x0;
        float py = -x1*z0 + y1*w0 + z1*x0 + w1*y0;
        float pz =  x1*y0 - y1*x0 + z1*w0 + w1*z0;
        if (f == 0) { pw = w1; px = x1; py = y1; pz = z1; }  // q_all[0] = qn[0]
        qall[f][0] = pw; qall[f][1] = px; qall[f][2] = py; qall[f][3] = pz;
        float o0 = 0.f, o1 = 0.f, o2 = 0.f;
        if (f >= 1) { o0 = off[7*f+0]; o1 = off[7*f+1]; o2 = off[7*f+2]; }
        tall[f][0] = tr[3*f+0] + o0;
        tall[f][1] = tr[3*f+1] + o1;
        tall[f][2] = tr[3*f+2] + o2;
    }
    __syncthreads();

    for (int j = t; j < F; j += blockDim.x) {
        const int fj = of[j];
        out_t[3*j+0] = tall[fj][0];
        out_t[3*j+1] = tall[fj][1];
        out_t[3*j+2] = tall[fj][2];
        out_q[4*j+0] = qall[fj][0];
        out_q[4*j+1] = qall[fj][1];
        out_q[4*j+2] = qall[fj][2];
        out_q[4*j+3] = qall[fj][3];

        float wj = (j == 0) ? 0.0f : (float)(of[j] - of[j-1]);

        float td = 0.0f;
        if (j >= 1) {
            const int fp = of[j-1];
            float ssum = 0.0f;
            #pragma unroll
            for (int c = 0; c < 3; ++c) {
                float d = fabsf(tall[fj][c] - tall[fp][c]);
                if (d < 0.2f) d = 0.0f;
                ssum += d * d;
            }
            td = wj * sqrtf(ssum);
        }
        out_td[j] = td;

        float qd;
        if (j == 0) {
            float sm = qall[F-1][0]*qall[F-1][0] + qall[F-1][1]*qall[F-1][1]
                     + qall[F-1][2]*qall[F-1][2] + qall[F-1][3]*qall[F-1][3];
            qd = wj * (1.0f - sm*sm);   // wj == 0
        } else {
            int ia = fj - 1;
            if (ia < 0) ia += F;        // JAX negative-index wrap
            float sm = qall[ia][0]*qall[fj][0] + qall[ia][1]*qall[fj][1]
                     + qall[ia][2]*qall[fj][2] + qall[ia][3]*qall[fj][3];
            qd = wj * (1.0f - sm*sm);
        }
        out_qd[j] = qd;
    }
}

// ---------------------------------------------------------------------------
// K2: texture copy — grid-stride, NT LOAD + PLAIN store (R5's proven combo:
// NT loads keep L2 free as the store write-combining buffer). This round's
// single A/B change vs R5: batch-4 load clustering (4 NT loads in flight
// before the 4 plain stores) — disambiguates R4's regression (which bundled
// batch-4 WITH NT stores). Vertex normalize runs AFTER the copy in the first
// blocks; finalize recomputed per-thread from the 32 partials (previous
// dispatch = coherence point, no grid sync).
// big = max over flattened centered array == max_c fl(mmax_c - center_c)
// (fl(x-c) is monotone in x, so the component max survives centering).
// ---------------------------------------------------------------------------
__global__ __launch_bounds__(256) void copy_finalize_norm_kernel(
    const f4* __restrict__ tex, f4* __restrict__ out_tex, long n_tex4,
    const float* __restrict__ partial,
    const f4* __restrict__ iv4, const f4* __restrict__ vp4,
    f4* __restrict__ out_v, int nv4)
{
    const int t = threadIdx.x;
    const long step = (long)gridDim.x * blockDim.x;

    // ---- texture copy: batch-4 NT loads, plain stores ----
    long i = (long)blockIdx.x * blockDim.x + t;
    for (; i + 3 * step < n_tex4; i += 4 * step) {
        f4 v0 = __builtin_nontemporal_load(&tex[i]);
        f4 v1 = __builtin_nontemporal_load(&tex[i +     step]);
        f4 v2 = __builtin_nontemporal_load(&tex[i + 2 * step]);
        f4 v3 = __builtin_nontemporal_load(&tex[i + 3 * step]);
        out_tex[i]            = v0;
        out_tex[i +     step] = v1;
        out_tex[i + 2 * step] = v2;
        out_tex[i + 3 * step] = v3;
    }
    for (; i < n_tex4; i += step) {
        out_tex[i] = __builtin_nontemporal_load(&tex[i]);
    }

    // ---- vertex normalize (first ceil(nv4/256) blocks, one f4/thread) ----
    const int gvid = blockIdx.x * blockDim.x + t;
    if (gvid < nv4) {
        float mx0=-FLT_MAX, mx1=-FLT_MAX, mx2=-FLT_MAX;
        float mn0= FLT_MAX, mn1= FLT_MAX, mn2= FLT_MAX;
        #pragma unroll
        for (int b = 0; b < RED_BLOCKS; ++b) {
            mx0 = fmaxf(mx0, partial[6*b+0]);
            mx1 = fmaxf(mx1, partial[6*b+1]);
            mx2 = fmaxf(mx2, partial[6*b+2]);
            mn0 = fminf(mn0, partial[6*b+3]);
            mn1 = fminf(mn1, partial[6*b+4]);
            mn2 = fminf(mn2, partial[6*b+5]);
        }
        const float c0 = (mx0 + mn0) * 0.5f;
        const float c1 = (mx1 + mn1) * 0.5f;
        const float c2 = (mx2 + mn2) * 0.5f;
        const float big = fmaxf(fmaxf(mx0 - c0, mx1 - c1), mx2 - c2);

        f4 a = iv4[gvid] + vp4[gvid];
        f4 r;
        // element 4*gvid+j has component (gvid+j)%3
        switch (gvid % 3) {
        case 0:
            r[0]=(a[0]-c0)/big; r[1]=(a[1]-c1)/big;
            r[2]=(a[2]-c2)/big; r[3]=(a[3]-c0)/big; break;
        case 1:
            r[0]=(a[0]-c1)/big; r[1]=(a[1]-c2)/big;
            r[2]=(a[2]-c0)/big; r[3]=(a[3]-c1)/big; break;
        default:
            r[0]=(a[0]-c2)/big; r[1]=(a[1]-c0)/big;
            r[2]=(a[2]-c1)/big; r[3]=(a[3]-c2)/big; break;
        }
        out_v[gvid] = r;
    }
}

// ---------------------------------------------------------------------------
extern "C" void kernel_launch(void* const* d_in, const int* in_sizes, int n_in,
                              void* d_out, int out_size, void* d_ws, size_t ws_size,
                              hipStream_t stream) {
    const float* tr  = (const float*)d_in[0];   // translation_p (1,1,F,3)
    const float* q   = (const float*)d_in[1];   // quaternion_p  (1,F,4)
    const float* vp  = (const float*)d_in[2];   // vertices_p    (1,V,3)
    const float* tex = (const float*)d_in[3];   // texture_map   (1,NF,T,T)
    const float* iv  = (const float*)d_in[4];   // ivertices     (1,V,3)
    const float* off = (const float*)d_in[5];   // offsets       (1,1,F,7)
    const int*   of  = (const int*)d_in[6];     // opt_frames    (F,)

    const int F    = in_sizes[6];
    const int nt   = in_sizes[0];   // F*3  = 720
    const int nq   = in_sizes[1];   // F*4  = 960
    const int nv   = in_sizes[2];   // V*3  = 300000 (div by 4)
    const int ntex = in_sizes[3];   // 67108864

    float* out     = (float*)d_out;
    float* out_t   = out;
    float* out_q   = out + nt;
    float* out_v   = out + nt + nq;              // float offset 1680   (%4==0)
    float* out_tex = out + nt + nq + nv;         // float offset 301680 (%4==0)
    float* out_td  = out + (size_t)nt + nq + nv + ntex;
    float* out_qd  = out_td + F;

    float* partial = (float*)d_ws;               // RED_BLOCKS*6 floats

    const int nv4 = nv / 4;

    minmax_frames_kernel<<<RED_BLOCKS + 1, 256, 0, stream>>>(
        (const f4*)iv, (const f4*)vp, nv4, partial,
        tr, q, off, of, out_t, out_q, out_td, out_qd, F);

    const long n_tex4 = (long)ntex / 4;
    copy_finalize_norm_kernel<<<COPY_GRID, 256, 0, stream>>>(
        (const f4*)tex, (f4*)out_tex, n_tex4,
        partial, (const f4*)iv, (const f4*)vp, (f4*)out_v, nv4);
}

// Round 8
// 90.407 us; speedup vs baseline: 1.3278x; 1.1902x over previous
//
#include <hip/hip_runtime.h>
#include <float.h>
#include <math.h>

#define F_MAX 512
#define RED_BLOCKS 32
#define COPY_GRID 1024   // R8 A/B: 2048 -> 1024 (4 blocks/CU; fill kernels hit 6.9 TB/s at ~3 waves/CU)

typedef float f4 __attribute__((ext_vector_type(4)));

// ---------------------------------------------------------------------------
// K1: block 0 = frame math only (quaternion normalize, qmult, t_all, gather
// by opt_frames, tdiff/qdiff). Blocks 1..RED_BLOCKS = per-component min/max
// partials over (iv+vp), f4-vectorized. Critical path = max, not sum.
// ---------------------------------------------------------------------------
__global__ __launch_bounds__(256) void minmax_frames_kernel(
    const f4* __restrict__ iv4, const f4* __restrict__ vp4, int nv4,
    float* __restrict__ partial,
    const float* __restrict__ tr,   // (1,1,F,3)
    const float* __restrict__ q,    // (1,F,4)
    const float* __restrict__ off,  // (1,1,F,7)
    const int*   __restrict__ of,   // (F,)
    float* __restrict__ out_t,      // (F,3)
    float* __restrict__ out_q,      // (F,4)
    float* __restrict__ out_td,     // (F,)
    float* __restrict__ out_qd,     // (F,)
    int F)
{
    const int t = threadIdx.x;

    if (blockIdx.x != 0) {
        // ---- min/max partial reduction, f4-vectorized ----
        // element 4*i+j has component (i+j)%3
        float mx0=-FLT_MAX, mx1=-FLT_MAX, mx2=-FLT_MAX;
        float mn0= FLT_MAX, mn1= FLT_MAX, mn2= FLT_MAX;
        const int gstride = (gridDim.x - 1) * blockDim.x;
        for (int i = (blockIdx.x - 1) * blockDim.x + t; i < nv4; i += gstride) {
            f4 a = iv4[i] + vp4[i];
            switch (i % 3) {
            case 0:
                mx0=fmaxf(mx0,a[0]); mn0=fminf(mn0,a[0]);
                mx1=fmaxf(mx1,a[1]); mn1=fminf(mn1,a[1]);
                mx2=fmaxf(mx2,a[2]); mn2=fminf(mn2,a[2]);
                mx0=fmaxf(mx0,a[3]); mn0=fminf(mn0,a[3]);
                break;
            case 1:
                mx1=fmaxf(mx1,a[0]); mn1=fminf(mn1,a[0]);
                mx2=fmaxf(mx2,a[1]); mn2=fminf(mn2,a[1]);
                mx0=fmaxf(mx0,a[2]); mn0=fminf(mn0,a[2]);
                mx1=fmaxf(mx1,a[3]); mn1=fminf(mn1,a[3]);
                break;
            default:
                mx2=fmaxf(mx2,a[0]); mn2=fminf(mn2,a[0]);
                mx0=fmaxf(mx0,a[1]); mn0=fminf(mn0,a[1]);
                mx1=fmaxf(mx1,a[2]); mn1=fminf(mn1,a[2]);
                mx2=fmaxf(mx2,a[3]); mn2=fminf(mn2,a[3]);
                break;
            }
        }
        __shared__ float s[256][6];
        s[t][0]=mx0; s[t][1]=mx1; s[t][2]=mx2; s[t][3]=mn0; s[t][4]=mn1; s[t][5]=mn2;
        __syncthreads();
        for (int w = 128; w >= 1; w >>= 1) {
            if (t < w) {
                s[t][0] = fmaxf(s[t][0], s[t+w][0]);
                s[t][1] = fmaxf(s[t][1], s[t+w][1]);
                s[t][2] = fmaxf(s[t][2], s[t+w][2]);
                s[t][3] = fminf(s[t][3], s[t+w][3]);
                s[t][4] = fminf(s[t][4], s[t+w][4]);
                s[t][5] = fminf(s[t][5], s[t+w][5]);
            }
            __syncthreads();
        }
        if (t == 0) {
            #pragma unroll
            for (int k = 0; k < 6; ++k)
                partial[(blockIdx.x - 1)*6 + k] = s[0][k];
        }
        return;
    }

    // ---- frame math (block 0 only) ----
    __shared__ float qall[F_MAX][4];
    __shared__ float tall[F_MAX][3];

    for (int f = t; f < F; f += blockDim.x) {
        float w1 = q[4*f+0], x1 = q[4*f+1], y1 = q[4*f+2], z1 = q[4*f+3];
        float n1 = sqrtf(w1*w1 + x1*x1 + y1*y1 + z1*z1);
        w1 /= n1; x1 /= n1; y1 /= n1; z1 /= n1;
        float w0 = off[7*f+3], x0 = off[7*f+4], y0 = off[7*f+5], z0 = off[7*f+6];
        float n0 = sqrtf(w0*w0 + x0*x0 + y0*y0 + z0*z0);
        w0 /= n0; x0 /= n0; y0 /= n0; z0 /= n0;
        float pw = -x1*x0 - y1*y0 - z1*z0 + w1*w0;
        float px =  x1*w0 + y1*z0 - z1*y0 + w1*x0;
        float py = -x1*z0 + y1*w0 + z1*x0 + w1*y0;
        float pz =  x1*y0 - y1*x0 + z1*w0 + w1*z0;
        if (f == 0) { pw = w1; px = x1; py = y1; pz = z1; }  // q_all[0] = qn[0]
        qall[f][0] = pw; qall[f][1] = px; qall[f][2] = py; qall[f][3] = pz;
        float o0 = 0.f, o1 = 0.f, o2 = 0.f;
        if (f >= 1) { o0 = off[7*f+0]; o1 = off[7*f+1]; o2 = off[7*f+2]; }
        tall[f][0] = tr[3*f+0] + o0;
        tall[f][1] = tr[3*f+1] + o1;
        tall[f][2] = tr[3*f+2] + o2;
    }
    __syncthreads();

    for (int j = t; j < F; j += blockDim.x) {
        const int fj = of[j];
        out_t[3*j+0] = tall[fj][0];
        out_t[3*j+1] = tall[fj][1];
        out_t[3*j+2] = tall[fj][2];
        out_q[4*j+0] = qall[fj][0];
        out_q[4*j+1] = qall[fj][1];
        out_q[4*j+2] = qall[fj][2];
        out_q[4*j+3] = qall[fj][3];

        float wj = (j == 0) ? 0.0f : (float)(of[j] - of[j-1]);

        float td = 0.0f;
        if (j >= 1) {
            const int fp = of[j-1];
            float ssum = 0.0f;
            #pragma unroll
            for (int c = 0; c < 3; ++c) {
                float d = fabsf(tall[fj][c] - tall[fp][c]);
                if (d < 0.2f) d = 0.0f;
                ssum += d * d;
            }
            td = wj * sqrtf(ssum);
        }
        out_td[j] = td;

        float qd;
        if (j == 0) {
            float sm = qall[F-1][0]*qall[F-1][0] + qall[F-1][1]*qall[F-1][1]
                     + qall[F-1][2]*qall[F-1][2] + qall[F-1][3]*qall[F-1][3];
            qd = wj * (1.0f - sm*sm);   // wj == 0
        } else {
            int ia = fj - 1;
            if (ia < 0) ia += F;        // JAX negative-index wrap
            float sm = qall[ia][0]*qall[fj][0] + qall[ia][1]*qall[fj][1]
                     + qall[ia][2]*qall[fj][2] + qall[ia][3]*qall[fj][3];
            qd = wj * (1.0f - sm*sm);
        }
        out_qd[j] = qd;
    }
}

// ---------------------------------------------------------------------------
// K2: texture copy — simple grid-stride, NT LOAD + PLAIN store (R5's proven
// combo: NT loads keep L2 free as the store write-combining buffer; simple
// loop lets the compiler pipeline — batching hurt, R7). R8's only change:
// COPY_GRID 2048 -> 1024 (fewer concurrent streams per channel; fill kernels
// reach 6.9 TB/s at ~3 waves/CU). Vertex normalize runs AFTER the copy in
// the first blocks; finalize recomputed per-thread from the 32 partials
// (previous dispatch = coherence point, no grid sync).
// big = max over flattened centered array == max_c fl(mmax_c - center_c)
// (fl(x-c) is monotone in x, so the component max survives centering).
// ---------------------------------------------------------------------------
__global__ __launch_bounds__(256) void copy_finalize_norm_kernel(
    const f4* __restrict__ tex, f4* __restrict__ out_tex, long n_tex4,
    const float* __restrict__ partial,
    const f4* __restrict__ iv4, const f4* __restrict__ vp4,
    f4* __restrict__ out_v, int nv4)
{
    const int t = threadIdx.x;
    const long nthreads = (long)gridDim.x * blockDim.x;

    // ---- texture copy ----
    for (long i = (long)blockIdx.x * blockDim.x + t; i < n_tex4; i += nthreads) {
        f4 v = __builtin_nontemporal_load(&tex[i]);
        out_tex[i] = v;
    }

    // ---- vertex normalize (first ceil(nv4/256) blocks, one f4/thread) ----
    const int gvid = blockIdx.x * blockDim.x + t;
    if (gvid < nv4) {
        float mx0=-FLT_MAX, mx1=-FLT_MAX, mx2=-FLT_MAX;
        float mn0= FLT_MAX, mn1= FLT_MAX, mn2= FLT_MAX;
        #pragma unroll
        for (int b = 0; b < RED_BLOCKS; ++b) {
            mx0 = fmaxf(mx0, partial[6*b+0]);
            mx1 = fmaxf(mx1, partial[6*b+1]);
            mx2 = fmaxf(mx2, partial[6*b+2]);
            mn0 = fminf(mn0, partial[6*b+3]);
            mn1 = fminf(mn1, partial[6*b+4]);
            mn2 = fminf(mn2, partial[6*b+5]);
        }
        const float c0 = (mx0 + mn0) * 0.5f;
        const float c1 = (mx1 + mn1) * 0.5f;
        const float c2 = (mx2 + mn2) * 0.5f;
        const float big = fmaxf(fmaxf(mx0 - c0, mx1 - c1), mx2 - c2);

        f4 a = iv4[gvid] + vp4[gvid];
        f4 r;
        // element 4*gvid+j has component (gvid+j)%3
        switch (gvid % 3) {
        case 0:
            r[0]=(a[0]-c0)/big; r[1]=(a[1]-c1)/big;
            r[2]=(a[2]-c2)/big; r[3]=(a[3]-c0)/big; break;
        case 1:
            r[0]=(a[0]-c1)/big; r[1]=(a[1]-c2)/big;
            r[2]=(a[2]-c0)/big; r[3]=(a[3]-c1)/big; break;
        default:
            r[0]=(a[0]-c2)/big; r[1]=(a[1]-c0)/big;
            r[2]=(a[2]-c1)/big; r[3]=(a[3]-c2)/big; break;
        }
        out_v[gvid] = r;
    }
}

// ---------------------------------------------------------------------------
extern "C" void kernel_launch(void* const* d_in, const int* in_sizes, int n_in,
                              void* d_out, int out_size, void* d_ws, size_t ws_size,
                              hipStream_t stream) {
    const float* tr  = (const float*)d_in[0];   // translation_p (1,1,F,3)
    const float* q   = (const float*)d_in[1];   // quaternion_p  (1,F,4)
    const float* vp  = (const float*)d_in[2];   // vertices_p    (1,V,3)
    const float* tex = (const float*)d_in[3];   // texture_map   (1,NF,T,T)
    const float* iv  = (const float*)d_in[4];   // ivertices     (1,V,3)
    const float* off = (const float*)d_in[5];   // offsets       (1,1,F,7)
    const int*   of  = (const int*)d_in[6];     // opt_frames    (F,)

    const int F    = in_sizes[6];
    const int nt   = in_sizes[0];   // F*3  = 720
    const int nq   = in_sizes[1];   // F*4  = 960
    const int nv   = in_sizes[2];   // V*3  = 300000 (div by 4)
    const int ntex = in_sizes[3];   // 67108864

    float* out     = (float*)d_out;
    float* out_t   = out;
    float* out_q   = out + nt;
    float* out_v   = out + nt + nq;              // float offset 1680   (%4==0)
    float* out_tex = out + nt + nq + nv;         // float offset 301680 (%4==0)
    float* out_td  = out + (size_t)nt + nq + nv + ntex;
    float* out_qd  = out_td + F;

    float* partial = (float*)d_ws;               // RED_BLOCKS*6 floats

    const int nv4 = nv / 4;

    minmax_frames_kernel<<<RED_BLOCKS + 1, 256, 0, stream>>>(
        (const f4*)iv, (const f4*)vp, nv4, partial,
        tr, q, off, of, out_t, out_q, out_td, out_qd, F);

    const long n_tex4 = (long)ntex / 4;
    copy_finalize_norm_kernel<<<COPY_GRID, 256, 0, stream>>>(
        (const f4*)tex, (f4*)out_tex, n_tex4,
        partial, (const f4*)iv, (const f4*)vp, (f4*)out_v, nv4);
}